// Round 18
// baseline (78.735 us; speedup 1.0000x reference)
//
#include <hip/hip_runtime.h>

typedef unsigned short u16;
typedef _Float16 f16;
typedef __attribute__((ext_vector_type(8))) _Float16 half8;
typedef __attribute__((ext_vector_type(4))) float f32x4;
typedef __attribute__((ext_vector_type(16))) float f32x16;

#define DEV __device__ __forceinline__

static constexpr int BATCH   = 16384;
static constexpr int NTAB    = 26;
static constexpr int VOCAB   = 100000;
static constexpr int DIM     = 64;

DEV u16 f2h(float f){ union { f16 h; u16 u; } x; x.h = (f16)f; return x.u; }

// async global->LDS, 16B per lane. dst must be the wave-uniform base; HW adds lane*16.
DEV void llds16(u16* dst, const u16* src){
  __builtin_amdgcn_global_load_lds(
      (const __attribute__((address_space(1))) unsigned*)src,
      (__attribute__((address_space(3))) unsigned*)dst, 16, 0, 0);
}

DEV int crow(int reg, int half){ return (reg & 3) + 8 * (reg >> 2) + 4 * half; }

// ---------------- prep: dense conv + tiled weight transpose (single fp16) ---------
DEV void wtile(const float* __restrict__ src, u16* __restrict__ dst,
               int K, int N, int Kpad, int tile)
{
  __shared__ float ld[32][33];
  const int nt = N >> 5;
  const int k0 = (tile / nt) << 5;
  const int n0 = (tile % nt) << 5;
  const int tx = threadIdx.x & 31;
  const int ty = threadIdx.x >> 5;
  #pragma unroll
  for (int it = 0; it < 4; ++it) {
    int k = k0 + ty + 8 * it;
    ld[ty + 8 * it][tx] = (k < K) ? src[(size_t)k * N + n0 + tx] : 0.f;
  }
  __syncthreads();
  #pragma unroll
  for (int it = 0; it < 4; ++it) {
    int n  = n0 + ty + 8 * it;
    int kp = k0 + tx;
    dst[(size_t)n * Kpad + kp] = f2h(ld[tx][ty + 8 * it]);
  }
}

__global__ void prep_k(const float* __restrict__ dense, u16* __restrict__ Xs,
                       const float* __restrict__ bw1, u16* __restrict__ W1s,
                       const float* __restrict__ bw2, u16* __restrict__ W2s,
                       const float* __restrict__ bw3, u16* __restrict__ W3s,
                       const float* __restrict__ tw1, u16* __restrict__ WT1s,
                       const float* __restrict__ tw2, u16* __restrict__ WT2s)
{
  int blk = blockIdx.x;
  if (blk < 128) {                        // dense: [B][13] -> [B][32] fp16 (0-pad)
    #pragma unroll
    for (int it = 0; it < 16; ++it) {
      int i = it * 32768 + blk * 256 + threadIdx.x;
      int b = i >> 5, k = i & 31;
      float v = (k < 13) ? dense[b * 13 + k] : 0.f;
      Xs[(size_t)b * 32 + k] = f2h(v);
    }
  }
  else if (blk < 144) wtile(bw1, W1s, 13, 512, 32,    blk - 128);  // 16
  else if (blk < 272) wtile(bw2, W2s, 512, 256, 512,  blk - 144);  // 128
  else if (blk < 288) wtile(bw3, W3s, 256, 64, 256,   blk - 272);  // 16
  else if (blk < 512) wtile(tw1, WT1s, 442, 512, 448, blk - 288);  // 224 (true K=448)
  else                wtile(tw2, WT2s, 512, 256, 512, blk - 512);  // 128
}

// ---------------- mega kernel: X -> dx -> gather+Gram -> top MLP -> out -----------
// One block = 64 batch rows, 8 waves, 1 block/CU. All intermediates live in LDS.
// K-loops use T4 depth-2 prefetch: {vmcnt(4); bar; MFMA(buf[t&1]);
// if(t+2<n){bar; stage(t+2, buf[t&1]);}} — stage waits are 2 iterations deep.
__global__ __launch_bounds__(512)
void mega_k(const u16* __restrict__ Xs, const u16* __restrict__ W1s,
            const u16* __restrict__ W2s, const u16* __restrict__ W3s,
            const float* __restrict__ bb1, const float* __restrict__ bb2,
            const float* __restrict__ bb3, const int* __restrict__ sidx,
            const float* __restrict__ tables, const u16* __restrict__ WT1s,
            const u16* __restrict__ WT2s, const float* __restrict__ tb1,
            const float* __restrict__ tb2, const float* __restrict__ tw3,
            const float* __restrict__ tb3, float* __restrict__ out)
{
  __shared__ alignas(16) u16 lds[71680];           // 140 KB
  __shared__ float redbuf[8][64];
  u16* AB   = lds;                                 // R0: A1 / I / B1
  u16* R1   = lds + 32768;
  u16* Xl   = R1;                                  // [64][32]  SW=3
  u16* W1l  = R1 + 2048;                           // [512][32] SW=3
  u16* W2b0 = R1 + 18432;                          // [256][64] SW=7
  u16* W2b1 = R1;
  u16* A2   = R1 + 18432;                          // [64][256] SW=31
  u16* W3l  = R1;                                  // [64][256] SW=31
  u16* dxl  = R1 + 34816;                          // [64][64] f16, SW=7 (16B slots)
  u16* Wb0  = R1;                                  // [256][64]-class tiles (32 KB)
  u16* Wb1  = R1 + 16384;

  const int tid = threadIdx.x, lane = tid & 63, wid = tid >> 6;
  int bid = blockIdx.x;
  bid = (bid & 7) * 32 + (bid >> 3);               // XCD swizzle (256 blocks)
  const int m0  = bid * 64;
  const int l31 = lane & 31, half = lane >> 5;

  // ======================= phase 1: bottom MLP -> dxl =======================
  auto stageW2 = [&](int t, u16* buf) {
    #pragma unroll
    for (int it = 0; it < 4; ++it) {
      int loff = (it * 512 + tid) * 16;
      int row  = loff >> 7, slot = (loff & 127) >> 4, gs = slot ^ (row & 7);
      llds16(buf + (size_t)(it * 512 + (wid << 6)) * 8,
             W2s + (size_t)row * 512 + t * 64 + gs * 8);
    }
  };

  if (tid < 256) {
    int loff = tid * 16, row = loff >> 6, slot = (loff & 63) >> 4, gs = slot ^ (row & 3);
    llds16(Xl + (size_t)(wid << 6) * 8, Xs + (size_t)(m0 + row) * 32 + gs * 8);
  }
  #pragma unroll
  for (int it = 0; it < 4; ++it) {
    int loff = (it * 512 + tid) * 16, row = loff >> 6, slot = (loff & 63) >> 4,
        gs = slot ^ (row & 3);
    llds16(W1l + (size_t)(it * 512 + (wid << 6)) * 8, W1s + (size_t)row * 32 + gs * 8);
  }
  stageW2(0, W2b0);
  asm volatile("s_waitcnt vmcnt(4)" ::: "memory");  // X+W1 landed; W2(0) flying
  __builtin_amdgcn_s_barrier();

  // G1: A1 = relu(X * W1^T + bb1), K=32; wave -> 64 cols
  {
    f32x16 acc1[2][2] = {};
    #pragma unroll
    for (int ks = 0; ks < 2; ++ks) {
      half8 af[2], bf[2];
      #pragma unroll
      for (int mi = 0; mi < 2; ++mi) {
        int row = mi * 32 + l31, sl = (2 * ks + half) ^ (row & 3);
        af[mi] = *(const half8*)(Xl + (size_t)row * 32 + sl * 8);
      }
      #pragma unroll
      for (int ni = 0; ni < 2; ++ni) {
        int row = wid * 64 + ni * 32 + l31, sl = (2 * ks + half) ^ (row & 3);
        bf[ni] = *(const half8*)(W1l + (size_t)row * 32 + sl * 8);
      }
      #pragma unroll
      for (int mi = 0; mi < 2; ++mi)
        #pragma unroll
        for (int ni = 0; ni < 2; ++ni)
          acc1[mi][ni] = __builtin_amdgcn_mfma_f32_32x32x16_f16(af[mi], bf[ni], acc1[mi][ni], 0, 0, 0);
    }
    #pragma unroll
    for (int ni = 0; ni < 2; ++ni) {
      int col = wid * 64 + ni * 32 + l31;
      float bv = bb1[col];
      #pragma unroll
      for (int mi = 0; mi < 2; ++mi)
        #pragma unroll
        for (int reg = 0; reg < 16; ++reg) {
          int row = mi * 32 + crow(reg, half);
          float v = fmaxf(acc1[mi][ni][reg] + bv, 0.f);
          AB[(size_t)row * 512 + (((col >> 3) ^ (row & 63)) * 8) + (col & 7)] = f2h(v);
        }
    }
  }
  __syncthreads();           // A1 visible; W1l/Xl dead

  // G2: A2 = relu(A1 * W2^T + bb2), K=512, 8 steps BK=64; T4 depth-2
  {
    stageW2(1, W2b1);        // W2b1 overlays dead W1l/Xl
    f32x16 acc2[2] = {};
    for (int t = 0; t < 8; ++t) {
      if (t < 7) asm volatile("s_waitcnt vmcnt(4)" ::: "memory");
      else       asm volatile("s_waitcnt vmcnt(0)" ::: "memory");
      __builtin_amdgcn_s_barrier();
      const u16* buf = (t & 1) ? W2b1 : W2b0;
      #pragma unroll
      for (int ks = 0; ks < 4; ++ks) {
        int s = t * 4 + ks;
        half8 af[2], bf;
        #pragma unroll
        for (int mi = 0; mi < 2; ++mi) {
          int row = mi * 32 + l31, sl = (2 * s + half) ^ (row & 63);
          af[mi] = *(const half8*)(AB + (size_t)row * 512 + sl * 8);
        }
        {
          int row = wid * 32 + l31, sl = (2 * ks + half) ^ (row & 7);
          bf = *(const half8*)(buf + (size_t)row * 64 + sl * 8);
        }
        #pragma unroll
        for (int mi = 0; mi < 2; ++mi)
          acc2[mi] = __builtin_amdgcn_mfma_f32_32x32x16_f16(af[mi], bf, acc2[mi], 0, 0, 0);
      }
      if (t + 2 < 8) {
        __builtin_amdgcn_s_barrier();                // buf[t&1] reads done block-wide
        stageW2(t + 2, (t & 1) ? W2b1 : W2b0);
      }
    }
    int col = wid * 32 + l31;
    float bv = bb2[col];
    #pragma unroll
    for (int mi = 0; mi < 2; ++mi)
      #pragma unroll
      for (int reg = 0; reg < 16; ++reg) {
        int row = mi * 32 + crow(reg, half);
        float v = fmaxf(acc2[mi][reg] + bv, 0.f);
        A2[(size_t)row * 256 + (((col >> 3) ^ (row & 31)) * 8) + (col & 7)] = f2h(v);
      }
  }
  __syncthreads();

  // stage full W3 [64][256] (32 KB)
  #pragma unroll
  for (int it = 0; it < 4; ++it) {
    int loff = (it * 512 + tid) * 16;
    int row = loff >> 9, slot = (loff & 511) >> 4, gs = slot ^ (row & 31);
    llds16(W3l + (size_t)(it * 512 + (wid << 6)) * 8, W3s + (size_t)row * 256 + gs * 8);
  }
  asm volatile("s_waitcnt vmcnt(0)" ::: "memory");
  __builtin_amdgcn_s_barrier();

  // G3: dx = relu(A2 * W3^T + bb3) -> dxl f16 (waves 0-3); SW=7 on 16B slots
  if (wid < 4) {
    f32x16 acc3 = {};
    const int gm = (wid >> 1) * 32, gn = (wid & 1) * 32;
    #pragma unroll
    for (int s = 0; s < 16; ++s) {
      int rowa = gm + l31, sa = (2 * s + half) ^ (rowa & 31);
      half8 a = *(const half8*)(A2 + (size_t)rowa * 256 + sa * 8);
      int rowb = gn + l31, sb = (2 * s + half) ^ (rowb & 31);
      half8 b = *(const half8*)(W3l + (size_t)rowb * 256 + sb * 8);
      acc3 = __builtin_amdgcn_mfma_f32_32x32x16_f16(a, b, acc3, 0, 0, 0);
    }
    #pragma unroll
    for (int reg = 0; reg < 16; ++reg) {
      int col = gn + l31, row = gm + crow(reg, half);
      float v = fmaxf(acc3[reg] + bb3[col], 0.f);
      dxl[(size_t)row * 64 + (((col >> 3) ^ (row & 7)) * 8) + (col & 7)] = f2h(v);
    }
  }
  __syncthreads();

  // ======================= phase 2: gather + Gram -> AB =====================
  // W4 tile [512][32] row-pair-packed; global WT1s is [512][448] (true K)
  auto stageW4 = [&](int t, u16* buf) {
    #pragma unroll
    for (int it = 0; it < 4; ++it) {
      int p  = (it * 512 + tid) * 16;
      int pr = p >> 7, ps = (p & 127) >> 4;
      int un = ps ^ (pr & 7);
      int row = 2 * pr + (un >> 2), ls = un & 3;
      llds16(buf + (size_t)(it * 512 + (wid << 6)) * 8,
             WT1s + (size_t)row * 448 + t * 32 + ls * 8);
    }
  };
  stageW4(0, Wb0);     // Wb0 overlays dead W3l; flies under the whole gather
  stageW4(1, Wb1);     // Wb1 overlays dead A2

  const int r = l31;
  auto gload = [&](int id, f32x4* buf) {
    if (r >= 1 && r <= 26) {
      const float* src = tables + ((size_t)(r - 1) * VOCAB + (size_t)id) * DIM;
      #pragma unroll
      for (int ks = 0; ks < 4; ++ks) {
        const float* p = src + ks * 16 + half * 8;
        buf[2 * ks]     = *(const f32x4*)(p);
        buf[2 * ks + 1] = *(const f32x4*)(p + 4);
      }
    }
  };
  auto gram = [&](int sr, const f32x4* buf) {
    {
      u16 dv = dxl[(size_t)sr * 64 + (((lane >> 3) ^ (sr & 7)) * 8) + (lane & 7)];
      AB[(size_t)sr * 512 + (((lane >> 3) ^ (sr & 63)) * 8) + (lane & 7)] = dv;
      if (lane < 6) {
        int c = 442 + lane;
        AB[(size_t)sr * 512 + (((c >> 3) ^ (sr & 63)) * 8) + (c & 7)] = 0;
      }
    }
    half8 fh[4];
    #pragma unroll
    for (int ks = 0; ks < 4; ++ks) {
      half8 h = {};
      if (r == 0) {
        int sl = (2 * ks + half) ^ (sr & 7);
        h = *(const half8*)(dxl + (size_t)sr * 64 + sl * 8);
      } else if (r <= 26) {
        f32x4 a = buf[2 * ks], c = buf[2 * ks + 1];
        #pragma unroll
        for (int j = 0; j < 4; ++j) { h[j] = (f16)a[j]; h[j + 4] = (f16)c[j]; }
      }
      fh[ks] = h;
    }
    f32x16 z = {};
    #pragma unroll
    for (int ks = 0; ks < 4; ++ks)
      z = __builtin_amdgcn_mfma_f32_32x32x16_f16(fh[ks], fh[ks], z, 0, 0, 0);
    if (r < 27) {
      #pragma unroll
      for (int reg = 0; reg < 16; ++reg) {
        int rw = crow(reg, half);
        if (rw <= r) {
          int c = 64 + rw * 27 - rw * (rw - 1) / 2 + (r - rw);
          AB[(size_t)sr * 512 + (((c >> 3) ^ (sr & 63)) * 8) + (c & 7)] = f2h(z[reg]);
        }
      }
    }
  };

  {
    f32x4 bufA[8], bufB[8];
    int id0 = (r >= 1 && r <= 26) ? sidx[(size_t)(m0 + wid * 8) * NTAB + (r - 1)] : 0;
    gload(id0, bufA);
    #pragma unroll
    for (int jj = 0; jj < 8; jj += 2) {
      if (jj + 1 < 8) {
        int id = (r >= 1 && r <= 26) ? sidx[(size_t)(m0 + wid * 8 + jj + 1) * NTAB + (r - 1)] : 0;
        gload(id, bufB);
      }
      gram(wid * 8 + jj, bufA);
      if (jj + 2 < 8) {
        int id = (r >= 1 && r <= 26) ? sidx[(size_t)(m0 + wid * 8 + jj + 2) * NTAB + (r - 1)] : 0;
        gload(id, bufA);
      }
      if (jj + 1 < 8) gram(wid * 8 + jj + 1, bufB);
    }
  }
  __syncthreads();

  // ======================= phase 3: top MLP -> out ==========================
  auto stageW5 = [&](int t, u16* buf) {
    #pragma unroll
    for (int it = 0; it < 4; ++it) {
      int loff = (it * 512 + tid) * 16;
      int row = loff >> 7, slot = (loff & 127) >> 4, gs = slot ^ (row & 7);
      llds16(buf + (size_t)(it * 512 + (wid << 6)) * 8,
             WT2s + (size_t)row * 512 + t * 64 + gs * 8);
    }
  };

  // G4: B1 = relu(I * WT1^T + tb1), K=448, 14 steps BK=32; T4 depth-2
  {
    f32x16 acc4[2][2] = {};
    for (int t = 0; t < 14; ++t) {
      if (t < 13) asm volatile("s_waitcnt vmcnt(4)" ::: "memory");
      else        asm volatile("s_waitcnt vmcnt(0)" ::: "memory");
      __builtin_amdgcn_s_barrier();
      const u16* buf = (t & 1) ? Wb1 : Wb0;
      #pragma unroll
      for (int ks = 0; ks < 2; ++ks) {
        int s = t * 2 + ks;
        half8 af[2], bf[2];
        #pragma unroll
        for (int mi = 0; mi < 2; ++mi) {
          int row = mi * 32 + l31, sl = (2 * s + half) ^ (row & 63);
          af[mi] = *(const half8*)(AB + (size_t)row * 512 + sl * 8);
        }
        #pragma unroll
        for (int ni = 0; ni < 2; ++ni) {
          int n = wid * 64 + ni * 32 + l31;
          int pr = n >> 1;
          int ps = (4 * (n & 1) + 2 * ks + half) ^ (pr & 7);
          bf[ni] = *(const half8*)(buf + (size_t)pr * 64 + ps * 8);
        }
        #pragma unroll
        for (int mi = 0; mi < 2; ++mi)
          #pragma unroll
          for (int ni = 0; ni < 2; ++ni)
            acc4[mi][ni] = __builtin_amdgcn_mfma_f32_32x32x16_f16(af[mi], bf[ni], acc4[mi][ni], 0, 0, 0);
      }
      if (t + 2 < 14) {
        __builtin_amdgcn_s_barrier();                // buf[t&1] reads done block-wide
        stageW4(t + 2, (t & 1) ? Wb1 : Wb0);
      }
    }
    __syncthreads();                                  // all I reads done
    stageW5(0, Wb0);                                  // W4 buffers dead; prefetch G5
    stageW5(1, Wb1);
    #pragma unroll
    for (int ni = 0; ni < 2; ++ni) {
      int col = wid * 64 + ni * 32 + l31;
      float bv = tb1[col];
      #pragma unroll
      for (int mi = 0; mi < 2; ++mi)
        #pragma unroll
        for (int reg = 0; reg < 16; ++reg) {
          int row = mi * 32 + crow(reg, half);
          float v = fmaxf(acc4[mi][ni][reg] + bv, 0.f);
          AB[(size_t)row * 512 + (((col >> 3) ^ (row & 63)) * 8) + (col & 7)] = f2h(v);
        }
    }
  }
  __syncthreads();

  // G5: y = relu(B1 * WT2^T + tb2), K=512, 8 steps BK=64; T4 depth-2; fused dot
  {
    f32x16 acc5[2] = {};
    for (int t = 0; t < 8; ++t) {
      if (t < 7) asm volatile("s_waitcnt vmcnt(4)" ::: "memory");
      else       asm volatile("s_waitcnt vmcnt(0)" ::: "memory");
      __builtin_amdgcn_s_barrier();
      const u16* buf = (t & 1) ? Wb1 : Wb0;
      #pragma unroll
      for (int ks = 0; ks < 4; ++ks) {
        int s = t * 4 + ks;
        half8 af[2], bf;
        #pragma unroll
        for (int mi = 0; mi < 2; ++mi) {
          int row = mi * 32 + l31, sl = (2 * s + half) ^ (row & 63);
          af[mi] = *(const half8*)(AB + (size_t)row * 512 + sl * 8);
        }
        {
          int row = wid * 32 + l31, sl = (2 * ks + half) ^ (row & 7);
          bf = *(const half8*)(buf + (size_t)row * 64 + sl * 8);
        }
        #pragma unroll
        for (int mi = 0; mi < 2; ++mi)
          acc5[mi] = __builtin_amdgcn_mfma_f32_32x32x16_f16(af[mi], bf, acc5[mi], 0, 0, 0);
      }
      if (t + 2 < 8) {
        __builtin_amdgcn_s_barrier();                // buf[t&1] reads done block-wide
        stageW5(t + 2, (t & 1) ? Wb1 : Wb0);
      }
    }
    int col = wid * 32 + l31;
    float bv = tb2[col], wv = tw3[col];
    #pragma unroll
    for (int mi = 0; mi < 2; ++mi)
      #pragma unroll
      for (int reg = 0; reg < 16; ++reg) {
        float s = fmaxf(acc5[mi][reg] + bv, 0.f) * wv;
        #pragma unroll
        for (int off = 16; off; off >>= 1) s += __shfl_xor(s, off);
        if (l31 == 0) redbuf[wid][mi * 32 + crow(reg, half)] = s;
      }
  }
  __syncthreads();
  if (tid < 64) {
    float s = tb3[0];
    #pragma unroll
    for (int w = 0; w < 8; ++w) s += redbuf[w][tid];
    out[m0 + tid] = 1.f / (1.f + expf(-s));
  }
}

// ----------------------------------------------------------------------------------
extern "C" void kernel_launch(void* const* d_in, const int* in_sizes, int n_in,
                              void* d_out, int out_size, void* d_ws, size_t ws_size,
                              hipStream_t stream)
{
  const float* dense  = (const float*)d_in[0];
  const int*   sidx   = (const int*)d_in[1];
  const float* tables = (const float*)d_in[2];
  const float* bw1 = (const float*)d_in[3];  const float* bb1 = (const float*)d_in[4];
  const float* bw2 = (const float*)d_in[5];  const float* bb2 = (const float*)d_in[6];
  const float* bw3 = (const float*)d_in[7];  const float* bb3 = (const float*)d_in[8];
  const float* tw1 = (const float*)d_in[9];  const float* tb1 = (const float*)d_in[10];
  const float* tw2 = (const float*)d_in[11]; const float* tb2 = (const float*)d_in[12];
  const float* tw3 = (const float*)d_in[13]; const float* tb3 = (const float*)d_in[14];
  float* out = (float*)d_out;

  char* ws = (char*)d_ws;
  size_t off = 0;
  auto alloc = [&](size_t bytes) { size_t o = off; off += (bytes + 1023) & ~(size_t)1023; return o; };

  u16*  Xs   = (u16*)(ws + alloc((size_t)BATCH * 32 * 2));    // [B][32]
  u16*  W1s  = (u16*)(ws + alloc((size_t)512 * 32 * 2));      // [512][32]
  u16*  W2s  = (u16*)(ws + alloc((size_t)256 * 512 * 2));     // [256][512]
  u16*  W3s  = (u16*)(ws + alloc((size_t)64 * 256 * 2));      // [64][256]
  u16*  WT1s = (u16*)(ws + alloc((size_t)512 * 448 * 2));     // [512][448] (true K)
  u16*  WT2s = (u16*)(ws + alloc((size_t)256 * 512 * 2));     // [256][512]
  (void)ws_size; (void)n_in; (void)in_sizes; (void)out_size;

  prep_k<<<640, 256, 0, stream>>>(dense, Xs, bw1, W1s, bw2, W2s, bw3, W3s,
                                  tw1, WT1s, tw2, WT2s);
  mega_k<<<256, 512, 0, stream>>>(Xs, W1s, W2s, W3s, bb1, bb2, bb3, sidx, tables,
                                  WT1s, WT2s, tb1, tb2, tw3, tb3, out);
}

// Round 19
// 65.525 us; speedup vs baseline: 1.2016x; 1.2016x over previous
//
#include <hip/hip_runtime.h>

typedef unsigned short u16;
typedef _Float16 f16;
typedef __attribute__((ext_vector_type(8))) _Float16 half8;
typedef __attribute__((ext_vector_type(4))) float f32x4;
typedef __attribute__((ext_vector_type(16))) float f32x16;

#define DEV __device__ __forceinline__

static constexpr int BATCH   = 16384;
static constexpr int NTAB    = 26;
static constexpr int VOCAB   = 100000;
static constexpr int DIM     = 64;

DEV u16 f2h(float f){ union { f16 h; u16 u; } x; x.h = (f16)f; return x.u; }

// async global->LDS, 16B per lane. dst must be the wave-uniform base; HW adds lane*16.
DEV void llds16(u16* dst, const u16* src){
  __builtin_amdgcn_global_load_lds(
      (const __attribute__((address_space(1))) unsigned*)src,
      (__attribute__((address_space(3))) unsigned*)dst, 16, 0, 0);
}

DEV int crow(int reg, int half){ return (reg & 3) + 8 * (reg >> 2) + 4 * half; }

// ---------------- prep: dense conv + tiled weight transpose (single fp16) ---------
DEV void wtile(const float* __restrict__ src, u16* __restrict__ dst,
               int K, int N, int Kpad, int tile)
{
  __shared__ float ld[32][33];
  const int nt = N >> 5;
  const int k0 = (tile / nt) << 5;
  const int n0 = (tile % nt) << 5;
  const int tx = threadIdx.x & 31;
  const int ty = threadIdx.x >> 5;
  #pragma unroll
  for (int it = 0; it < 4; ++it) {
    int k = k0 + ty + 8 * it;
    ld[ty + 8 * it][tx] = (k < K) ? src[(size_t)k * N + n0 + tx] : 0.f;
  }
  __syncthreads();
  #pragma unroll
  for (int it = 0; it < 4; ++it) {
    int n  = n0 + ty + 8 * it;
    int kp = k0 + tx;
    dst[(size_t)n * Kpad + kp] = f2h(ld[tx][ty + 8 * it]);
  }
}

__global__ void prep_k(const float* __restrict__ dense, u16* __restrict__ Xs,
                       const float* __restrict__ bw1, u16* __restrict__ W1s,
                       const float* __restrict__ bw2, u16* __restrict__ W2s,
                       const float* __restrict__ bw3, u16* __restrict__ W3s,
                       const float* __restrict__ tw1, u16* __restrict__ WT1s,
                       const float* __restrict__ tw2, u16* __restrict__ WT2s)
{
  int blk = blockIdx.x;
  if (blk < 128) {                        // dense: [B][13] -> [B][32] fp16 (0-pad)
    #pragma unroll
    for (int it = 0; it < 16; ++it) {
      int i = it * 32768 + blk * 256 + threadIdx.x;
      int b = i >> 5, k = i & 31;
      float v = (k < 13) ? dense[b * 13 + k] : 0.f;
      Xs[(size_t)b * 32 + k] = f2h(v);
    }
  }
  else if (blk < 144) wtile(bw1, W1s, 13, 512, 32,    blk - 128);  // 16
  else if (blk < 272) wtile(bw2, W2s, 512, 256, 512,  blk - 144);  // 128
  else if (blk < 288) wtile(bw3, W3s, 256, 64, 256,   blk - 272);  // 16
  else if (blk < 512) wtile(tw1, WT1s, 442, 512, 448, blk - 288);  // 224 (true K=448)
  else                wtile(tw2, WT2s, 512, 256, 512, blk - 512);  // 128
}

// ---------------- mega kernel: X -> dx -> gather+Gram -> top MLP -> out -----------
// One block = 64 batch rows, 8 waves, 1 block/CU. All intermediates live in LDS.
// K-loops: T3-min depth-1 (one vmcnt(0) + one barrier per step). Phase-boundary
// stages (W3, G5's stage0) are issued under the preceding GEMM's epilogue via the
// R13-proven raw lgkmcnt-barrier pattern.
__global__ __launch_bounds__(512)
void mega_k(const u16* __restrict__ Xs, const u16* __restrict__ W1s,
            const u16* __restrict__ W2s, const u16* __restrict__ W3s,
            const float* __restrict__ bb1, const float* __restrict__ bb2,
            const float* __restrict__ bb3, const int* __restrict__ sidx,
            const float* __restrict__ tables, const u16* __restrict__ WT1s,
            const u16* __restrict__ WT2s, const float* __restrict__ tb1,
            const float* __restrict__ tb2, const float* __restrict__ tw3,
            const float* __restrict__ tb3, float* __restrict__ out)
{
  __shared__ alignas(16) u16 lds[71680];           // 140 KB
  __shared__ float redbuf[8][64];
  u16* AB   = lds;                                 // R0: A1 / I / B1
  u16* R1   = lds + 32768;
  u16* Xl   = R1;                                  // [64][32]  SW=3
  u16* W1l  = R1 + 2048;                           // [512][32] SW=3
  u16* W2b0 = R1 + 18432;                          // [256][64] SW=7
  u16* W2b1 = R1;
  u16* A2   = R1 + 18432;                          // [64][256] SW=31
  u16* W3l  = R1;                                  // [64][256] SW=31
  u16* dxl  = R1 + 34816;                          // [64][64] f16, SW=7 (16B slots)
  u16* Wb0  = R1;                                  // [256][64]-class tiles (32 KB)
  u16* Wb1  = R1 + 16384;

  const int tid = threadIdx.x, lane = tid & 63, wid = tid >> 6;
  int bid = blockIdx.x;
  bid = (bid & 7) * 32 + (bid >> 3);               // XCD swizzle (256 blocks)
  const int m0  = bid * 64;
  const int l31 = lane & 31, half = lane >> 5;

  // ======================= phase 1: bottom MLP -> dxl =======================
  auto stageW2 = [&](int t, u16* buf) {
    #pragma unroll
    for (int it = 0; it < 4; ++it) {
      int loff = (it * 512 + tid) * 16;
      int row  = loff >> 7, slot = (loff & 127) >> 4, gs = slot ^ (row & 7);
      llds16(buf + (size_t)(it * 512 + (wid << 6)) * 8,
             W2s + (size_t)row * 512 + t * 64 + gs * 8);
    }
  };

  if (tid < 256) {
    int loff = tid * 16, row = loff >> 6, slot = (loff & 63) >> 4, gs = slot ^ (row & 3);
    llds16(Xl + (size_t)(wid << 6) * 8, Xs + (size_t)(m0 + row) * 32 + gs * 8);
  }
  #pragma unroll
  for (int it = 0; it < 4; ++it) {
    int loff = (it * 512 + tid) * 16, row = loff >> 6, slot = (loff & 63) >> 4,
        gs = slot ^ (row & 3);
    llds16(W1l + (size_t)(it * 512 + (wid << 6)) * 8, W1s + (size_t)row * 32 + gs * 8);
  }
  stageW2(0, W2b0);
  asm volatile("s_waitcnt vmcnt(4)" ::: "memory");  // X+W1 landed; W2(0) flying
  __builtin_amdgcn_s_barrier();

  // G1: A1 = relu(X * W1^T + bb1), K=32; wave -> 64 cols
  {
    f32x16 acc1[2][2] = {};
    #pragma unroll
    for (int ks = 0; ks < 2; ++ks) {
      half8 af[2], bf[2];
      #pragma unroll
      for (int mi = 0; mi < 2; ++mi) {
        int row = mi * 32 + l31, sl = (2 * ks + half) ^ (row & 3);
        af[mi] = *(const half8*)(Xl + (size_t)row * 32 + sl * 8);
      }
      #pragma unroll
      for (int ni = 0; ni < 2; ++ni) {
        int row = wid * 64 + ni * 32 + l31, sl = (2 * ks + half) ^ (row & 3);
        bf[ni] = *(const half8*)(W1l + (size_t)row * 32 + sl * 8);
      }
      #pragma unroll
      for (int mi = 0; mi < 2; ++mi)
        #pragma unroll
        for (int ni = 0; ni < 2; ++ni)
          acc1[mi][ni] = __builtin_amdgcn_mfma_f32_32x32x16_f16(af[mi], bf[ni], acc1[mi][ni], 0, 0, 0);
    }
    #pragma unroll
    for (int ni = 0; ni < 2; ++ni) {
      int col = wid * 64 + ni * 32 + l31;
      float bv = bb1[col];
      #pragma unroll
      for (int mi = 0; mi < 2; ++mi)
        #pragma unroll
        for (int reg = 0; reg < 16; ++reg) {
          int row = mi * 32 + crow(reg, half);
          float v = fmaxf(acc1[mi][ni][reg] + bv, 0.f);
          AB[(size_t)row * 512 + (((col >> 3) ^ (row & 63)) * 8) + (col & 7)] = f2h(v);
        }
    }
  }
  __syncthreads();

  // G2: A2 = relu(A1 * W2^T + bb2), K=512, 8 steps BK=64; wave -> 32 cols
  {
    f32x16 acc2[2] = {};
    for (int t = 0; t < 8; ++t) {
      asm volatile("s_waitcnt vmcnt(0)" ::: "memory");
      __builtin_amdgcn_s_barrier();
      if (t < 7) stageW2(t + 1, ((t + 1) & 1) ? W2b1 : W2b0);
      const u16* buf = (t & 1) ? W2b1 : W2b0;
      #pragma unroll
      for (int ks = 0; ks < 4; ++ks) {
        int s = t * 4 + ks;
        half8 af[2], bf;
        #pragma unroll
        for (int mi = 0; mi < 2; ++mi) {
          int row = mi * 32 + l31, sl = (2 * s + half) ^ (row & 63);
          af[mi] = *(const half8*)(AB + (size_t)row * 512 + sl * 8);
        }
        {
          int row = wid * 32 + l31, sl = (2 * ks + half) ^ (row & 7);
          bf = *(const half8*)(buf + (size_t)row * 64 + sl * 8);
        }
        #pragma unroll
        for (int mi = 0; mi < 2; ++mi)
          acc2[mi] = __builtin_amdgcn_mfma_f32_32x32x16_f16(af[mi], bf, acc2[mi], 0, 0, 0);
      }
    }
    // all W2 ds_reads done block-wide; stage W3 (overlays dead W2b1) under epilogue
    asm volatile("s_waitcnt lgkmcnt(0)" ::: "memory");
    __builtin_amdgcn_s_barrier();
    #pragma unroll
    for (int it = 0; it < 4; ++it) {
      int loff = (it * 512 + tid) * 16;
      int row = loff >> 9, slot = (loff & 511) >> 4, gs = slot ^ (row & 31);
      llds16(W3l + (size_t)(it * 512 + (wid << 6)) * 8, W3s + (size_t)row * 256 + gs * 8);
    }
    // epilogue -> A2 (overlays dead W2b0)
    int col = wid * 32 + l31;
    float bv = bb2[col];
    #pragma unroll
    for (int mi = 0; mi < 2; ++mi)
      #pragma unroll
      for (int reg = 0; reg < 16; ++reg) {
        int row = mi * 32 + crow(reg, half);
        float v = fmaxf(acc2[mi][reg] + bv, 0.f);
        A2[(size_t)row * 256 + (((col >> 3) ^ (row & 31)) * 8) + (col & 7)] = f2h(v);
      }
  }
  asm volatile("s_waitcnt vmcnt(0) lgkmcnt(0)" ::: "memory");  // W3 landed; A2 visible
  __builtin_amdgcn_s_barrier();

  // G3: dx = relu(A2 * W3^T + bb3) -> dxl f16 (waves 0-3); SW=7 on 16B slots
  if (wid < 4) {
    f32x16 acc3 = {};
    const int gm = (wid >> 1) * 32, gn = (wid & 1) * 32;
    #pragma unroll
    for (int s = 0; s < 16; ++s) {
      int rowa = gm + l31, sa = (2 * s + half) ^ (rowa & 31);
      half8 a = *(const half8*)(A2 + (size_t)rowa * 256 + sa * 8);
      int rowb = gn + l31, sb = (2 * s + half) ^ (rowb & 31);
      half8 b = *(const half8*)(W3l + (size_t)rowb * 256 + sb * 8);
      acc3 = __builtin_amdgcn_mfma_f32_32x32x16_f16(a, b, acc3, 0, 0, 0);
    }
    #pragma unroll
    for (int reg = 0; reg < 16; ++reg) {
      int col = gn + l31, row = gm + crow(reg, half);
      float v = fmaxf(acc3[reg] + bb3[col], 0.f);
      dxl[(size_t)row * 64 + (((col >> 3) ^ (row & 7)) * 8) + (col & 7)] = f2h(v);
    }
  }
  __syncthreads();

  // ======================= phase 2: gather + Gram -> AB =====================
  // W4 tile [512][32] row-pair-packed; global WT1s is [512][448] (true K)
  auto stageW4 = [&](int t, u16* buf) {
    #pragma unroll
    for (int it = 0; it < 4; ++it) {
      int p  = (it * 512 + tid) * 16;
      int pr = p >> 7, ps = (p & 127) >> 4;
      int un = ps ^ (pr & 7);
      int row = 2 * pr + (un >> 2), ls = un & 3;
      llds16(buf + (size_t)(it * 512 + (wid << 6)) * 8,
             WT1s + (size_t)row * 448 + t * 32 + ls * 8);
    }
  };
  stageW4(0, Wb0);     // overlays dead W3l; flies under the whole gather

  const int r = l31;
  auto gload = [&](int id, f32x4* buf) {
    if (r >= 1 && r <= 26) {
      const float* src = tables + ((size_t)(r - 1) * VOCAB + (size_t)id) * DIM;
      #pragma unroll
      for (int ks = 0; ks < 4; ++ks) {
        const float* p = src + ks * 16 + half * 8;
        buf[2 * ks]     = *(const f32x4*)(p);
        buf[2 * ks + 1] = *(const f32x4*)(p + 4);
      }
    }
  };
  auto gram = [&](int sr, const f32x4* buf) {
    {
      u16 dv = dxl[(size_t)sr * 64 + (((lane >> 3) ^ (sr & 7)) * 8) + (lane & 7)];
      AB[(size_t)sr * 512 + (((lane >> 3) ^ (sr & 63)) * 8) + (lane & 7)] = dv;
      if (lane < 6) {
        int c = 442 + lane;
        AB[(size_t)sr * 512 + (((c >> 3) ^ (sr & 63)) * 8) + (c & 7)] = 0;
      }
    }
    half8 fh[4];
    #pragma unroll
    for (int ks = 0; ks < 4; ++ks) {
      half8 h = {};
      if (r == 0) {
        int sl = (2 * ks + half) ^ (sr & 7);
        h = *(const half8*)(dxl + (size_t)sr * 64 + sl * 8);
      } else if (r <= 26) {
        f32x4 a = buf[2 * ks], c = buf[2 * ks + 1];
        #pragma unroll
        for (int j = 0; j < 4; ++j) { h[j] = (f16)a[j]; h[j + 4] = (f16)c[j]; }
      }
      fh[ks] = h;
    }
    f32x16 z = {};
    #pragma unroll
    for (int ks = 0; ks < 4; ++ks)
      z = __builtin_amdgcn_mfma_f32_32x32x16_f16(fh[ks], fh[ks], z, 0, 0, 0);
    if (r < 27) {
      #pragma unroll
      for (int reg = 0; reg < 16; ++reg) {
        int rw = crow(reg, half);
        if (rw <= r) {
          int c = 64 + rw * 27 - rw * (rw - 1) / 2 + (r - rw);
          AB[(size_t)sr * 512 + (((c >> 3) ^ (sr & 63)) * 8) + (c & 7)] = f2h(z[reg]);
        }
      }
    }
  };

  {
    f32x4 bufA[8], bufB[8];
    int id0 = (r >= 1 && r <= 26) ? sidx[(size_t)(m0 + wid * 8) * NTAB + (r - 1)] : 0;
    gload(id0, bufA);
    #pragma unroll
    for (int jj = 0; jj < 8; jj += 2) {
      if (jj + 1 < 8) {
        int id = (r >= 1 && r <= 26) ? sidx[(size_t)(m0 + wid * 8 + jj + 1) * NTAB + (r - 1)] : 0;
        gload(id, bufB);
      }
      gram(wid * 8 + jj, bufA);
      if (jj + 2 < 8) {
        int id = (r >= 1 && r <= 26) ? sidx[(size_t)(m0 + wid * 8 + jj + 2) * NTAB + (r - 1)] : 0;
        gload(id, bufA);
      }
      if (jj + 1 < 8) gram(wid * 8 + jj + 1, bufB);
    }
  }
  __syncthreads();

  // ======================= phase 3: top MLP -> out ==========================
  auto stageW5 = [&](int t, u16* buf) {
    #pragma unroll
    for (int it = 0; it < 4; ++it) {
      int loff = (it * 512 + tid) * 16;
      int row = loff >> 7, slot = (loff & 127) >> 4, gs = slot ^ (row & 7);
      llds16(buf + (size_t)(it * 512 + (wid << 6)) * 8,
             WT2s + (size_t)row * 512 + t * 64 + gs * 8);
    }
  };

  // G4: B1 = relu(I * WT1^T + tb1), K=448, 14 steps BK=32; wave -> 64 cols
  {
    f32x16 acc4[2][2] = {};
    for (int t = 0; t < 14; ++t) {
      asm volatile("s_waitcnt vmcnt(0)" ::: "memory");
      __builtin_amdgcn_s_barrier();
      if (t < 13) stageW4(t + 1, ((t + 1) & 1) ? Wb1 : Wb0);
      const u16* buf = (t & 1) ? Wb1 : Wb0;
      #pragma unroll
      for (int ks = 0; ks < 2; ++ks) {
        int s = t * 2 + ks;
        half8 af[2], bf[2];
        #pragma unroll
        for (int mi = 0; mi < 2; ++mi) {
          int row = mi * 32 + l31, sl = (2 * s + half) ^ (row & 63);
          af[mi] = *(const half8*)(AB + (size_t)row * 512 + sl * 8);
        }
        #pragma unroll
        for (int ni = 0; ni < 2; ++ni) {
          int n = wid * 64 + ni * 32 + l31;
          int pr = n >> 1;
          int ps = (4 * (n & 1) + 2 * ks + half) ^ (pr & 7);
          bf[ni] = *(const half8*)(buf + (size_t)pr * 64 + ps * 8);
        }
        #pragma unroll
        for (int mi = 0; mi < 2; ++mi)
          #pragma unroll
          for (int ni = 0; ni < 2; ++ni)
            acc4[mi][ni] = __builtin_amdgcn_mfma_f32_32x32x16_f16(af[mi], bf[ni], acc4[mi][ni], 0, 0, 0);
      }
    }
    // all I reads + Wb reads done block-wide; stage G5's first tile under epilogue
    asm volatile("s_waitcnt lgkmcnt(0)" ::: "memory");
    __builtin_amdgcn_s_barrier();
    stageW5(0, Wb0);                                  // Wb0 last read t=12; dead
    #pragma unroll
    for (int ni = 0; ni < 2; ++ni) {
      int col = wid * 64 + ni * 32 + l31;
      float bv = tb1[col];
      #pragma unroll
      for (int mi = 0; mi < 2; ++mi)
        #pragma unroll
        for (int reg = 0; reg < 16; ++reg) {
          int row = mi * 32 + crow(reg, half);
          float v = fmaxf(acc4[mi][ni][reg] + bv, 0.f);
          AB[(size_t)row * 512 + (((col >> 3) ^ (row & 63)) * 8) + (col & 7)] = f2h(v);
        }
    }
  }
  asm volatile("s_waitcnt lgkmcnt(0)" ::: "memory");  // B1 visible; stage keeps flying
  __builtin_amdgcn_s_barrier();

  // G5: y = relu(B1 * WT2^T + tb2), K=512, 8 steps BK=64; fused final dot
  {
    f32x16 acc5[2] = {};
    for (int t = 0; t < 8; ++t) {
      asm volatile("s_waitcnt vmcnt(0)" ::: "memory");
      __builtin_amdgcn_s_barrier();
      if (t < 7) stageW5(t + 1, ((t + 1) & 1) ? Wb1 : Wb0);
      const u16* buf = (t & 1) ? Wb1 : Wb0;
      #pragma unroll
      for (int ks = 0; ks < 4; ++ks) {
        int s = t * 4 + ks;
        half8 af[2], bf;
        #pragma unroll
        for (int mi = 0; mi < 2; ++mi) {
          int row = mi * 32 + l31, sl = (2 * s + half) ^ (row & 63);
          af[mi] = *(const half8*)(AB + (size_t)row * 512 + sl * 8);
        }
        {
          int row = wid * 32 + l31, sl = (2 * ks + half) ^ (row & 7);
          bf = *(const half8*)(buf + (size_t)row * 64 + sl * 8);
        }
        #pragma unroll
        for (int mi = 0; mi < 2; ++mi)
          acc5[mi] = __builtin_amdgcn_mfma_f32_32x32x16_f16(af[mi], bf, acc5[mi], 0, 0, 0);
      }
    }
    int col = wid * 32 + l31;
    float bv = tb2[col], wv = tw3[col];
    #pragma unroll
    for (int mi = 0; mi < 2; ++mi)
      #pragma unroll
      for (int reg = 0; reg < 16; ++reg) {
        float s = fmaxf(acc5[mi][reg] + bv, 0.f) * wv;
        #pragma unroll
        for (int off = 16; off; off >>= 1) s += __shfl_xor(s, off);
        if (l31 == 0) redbuf[wid][mi * 32 + crow(reg, half)] = s;
      }
  }
  __syncthreads();
  if (tid < 64) {
    float s = tb3[0];
    #pragma unroll
    for (int w = 0; w < 8; ++w) s += redbuf[w][tid];
    out[m0 + tid] = 1.f / (1.f + expf(-s));
  }
}

// ----------------------------------------------------------------------------------
extern "C" void kernel_launch(void* const* d_in, const int* in_sizes, int n_in,
                              void* d_out, int out_size, void* d_ws, size_t ws_size,
                              hipStream_t stream)
{
  const float* dense  = (const float*)d_in[0];
  const int*   sidx   = (const int*)d_in[1];
  const float* tables = (const float*)d_in[2];
  const float* bw1 = (const float*)d_in[3];  const float* bb1 = (const float*)d_in[4];
  const float* bw2 = (const float*)d_in[5];  const float* bb2 = (const float*)d_in[6];
  const float* bw3 = (const float*)d_in[7];  const float* bb3 = (const float*)d_in[8];
  const float* tw1 = (const float*)d_in[9];  const float* tb1 = (const float*)d_in[10];
  const float* tw2 = (const float*)d_in[11]; const float* tb2 = (const float*)d_in[12];
  const float* tw3 = (const float*)d_in[13]; const float* tb3 = (const float*)d_in[14];
  float* out = (float*)d_out;

  char* ws = (char*)d_ws;
  size_t off = 0;
  auto alloc = [&](size_t bytes) { size_t o = off; off += (bytes + 1023) & ~(size_t)1023; return o; };

  u16*  Xs   = (u16*)(ws + alloc((size_t)BATCH * 32 * 2));    // [B][32]
  u16*  W1s  = (u16*)(ws + alloc((size_t)512 * 32 * 2));      // [512][32]
  u16*  W2s  = (u16*)(ws + alloc((size_t)256 * 512 * 2));     // [256][512]
  u16*  W3s  = (u16*)(ws + alloc((size_t)64 * 256 * 2));      // [64][256]
  u16*  WT1s = (u16*)(ws + alloc((size_t)512 * 448 * 2));     // [512][448] (true K)
  u16*  WT2s = (u16*)(ws + alloc((size_t)256 * 512 * 2));     // [256][512]
  (void)ws_size; (void)n_in; (void)in_sizes; (void)out_size;

  prep_k<<<640, 256, 0, stream>>>(dense, Xs, bw1, W1s, bw2, W2s, bw3, W3s,
                                  tw1, WT1s, tw2, WT2s);
  mega_k<<<256, 512, 0, stream>>>(Xs, W1s, W2s, W3s, bb1, bb2, bb3, sidx, tables,
                                  WT1s, WT2s, tb1, tb2, tw3, tb3, out);
}

// Round 20
// 63.568 us; speedup vs baseline: 1.2386x; 1.0308x over previous
//
#include <hip/hip_runtime.h>

typedef unsigned short u16;
typedef _Float16 f16;
typedef __attribute__((ext_vector_type(8))) _Float16 half8;
typedef __attribute__((ext_vector_type(4))) float f32x4;
typedef __attribute__((ext_vector_type(16))) float f32x16;

#define DEV __device__ __forceinline__

static constexpr int BATCH   = 16384;
static constexpr int NTAB    = 26;
static constexpr int VOCAB   = 100000;
static constexpr int DIM     = 64;

DEV u16 f2h(float f){ union { f16 h; u16 u; } x; x.h = (f16)f; return x.u; }

// async global->LDS, 16B per lane. dst must be the wave-uniform base; HW adds lane*16.
DEV void llds16(u16* dst, const u16* src){
  __builtin_amdgcn_global_load_lds(
      (const __attribute__((address_space(1))) unsigned*)src,
      (__attribute__((address_space(3))) unsigned*)dst, 16, 0, 0);
}

DEV int crow(int reg, int half){ return (reg & 3) + 8 * (reg >> 2) + 4 * half; }

// ---------------- prep: dense conv + tiled weight transpose (single fp16) ---------
DEV void wtile(const float* __restrict__ src, u16* __restrict__ dst,
               int K, int N, int Kpad, int tile)
{
  __shared__ float ld[32][33];
  const int nt = N >> 5;
  const int k0 = (tile / nt) << 5;
  const int n0 = (tile % nt) << 5;
  const int tx = threadIdx.x & 31;
  const int ty = threadIdx.x >> 5;
  #pragma unroll
  for (int it = 0; it < 4; ++it) {
    int k = k0 + ty + 8 * it;
    ld[ty + 8 * it][tx] = (k < K) ? src[(size_t)k * N + n0 + tx] : 0.f;
  }
  __syncthreads();
  #pragma unroll
  for (int it = 0; it < 4; ++it) {
    int n  = n0 + ty + 8 * it;
    int kp = k0 + tx;
    dst[(size_t)n * Kpad + kp] = f2h(ld[tx][ty + 8 * it]);
  }
}

__global__ void prep_k(const float* __restrict__ dense, u16* __restrict__ Xs,
                       const float* __restrict__ bw1, u16* __restrict__ W1s,
                       const float* __restrict__ bw2, u16* __restrict__ W2s,
                       const float* __restrict__ bw3, u16* __restrict__ W3s,
                       const float* __restrict__ tw1, u16* __restrict__ WT1s,
                       const float* __restrict__ tw2, u16* __restrict__ WT2s)
{
  int blk = blockIdx.x;
  if (blk < 128) {                        // dense: [B][13] -> [B][32] fp16 (0-pad)
    #pragma unroll
    for (int it = 0; it < 16; ++it) {
      int i = it * 32768 + blk * 256 + threadIdx.x;
      int b = i >> 5, k = i & 31;
      float v = (k < 13) ? dense[b * 13 + k] : 0.f;
      Xs[(size_t)b * 32 + k] = f2h(v);
    }
  }
  else if (blk < 144) wtile(bw1, W1s, 13, 512, 32,    blk - 128);  // 16
  else if (blk < 272) wtile(bw2, W2s, 512, 256, 512,  blk - 144);  // 128
  else if (blk < 288) wtile(bw3, W3s, 256, 64, 256,   blk - 272);  // 16
  else if (blk < 512) wtile(tw1, WT1s, 442, 512, 448, blk - 288);  // 224 (true K=448)
  else                wtile(tw2, WT2s, 512, 256, 512, blk - 512);  // 128
}

// ---------------- mega kernel: X -> dx -> gather+Gram -> top MLP -> out -----------
// One block = 64 batch rows, 8 waves, 1 block/CU. All intermediates live in LDS.
// K-loops: T3-min depth-1. Phase-boundary stages hidden under preceding work:
// W3 under G2 epilogue; W4 tiles 0+1 under the gather; W5 tiles 0+1 under the
// B1 epilogue (R13-proven raw lgkmcnt-barrier pattern).
__global__ __launch_bounds__(512)
void mega_k(const u16* __restrict__ Xs, const u16* __restrict__ W1s,
            const u16* __restrict__ W2s, const u16* __restrict__ W3s,
            const float* __restrict__ bb1, const float* __restrict__ bb2,
            const float* __restrict__ bb3, const int* __restrict__ sidx,
            const float* __restrict__ tables, const u16* __restrict__ WT1s,
            const u16* __restrict__ WT2s, const float* __restrict__ tb1,
            const float* __restrict__ tb2, const float* __restrict__ tw3,
            const float* __restrict__ tb3, float* __restrict__ out)
{
  __shared__ alignas(16) u16 lds[71680];           // 140 KB
  __shared__ float redbuf[8][64];
  u16* AB   = lds;                                 // R0: A1 / I / B1
  u16* R1   = lds + 32768;
  u16* Xl   = R1;                                  // [64][32]  SW=3
  u16* W1l  = R1 + 2048;                           // [512][32] SW=3
  u16* W2b0 = R1 + 18432;                          // [256][64] SW=7
  u16* W2b1 = R1;
  u16* A2   = R1 + 18432;                          // [64][256] SW=31
  u16* W3l  = R1;                                  // [64][256] SW=31
  u16* dxl  = R1 + 34816;                          // [64][64] f16, SW=7 (16B slots)
  u16* Wb0  = R1;                                  // [256][64]-class tiles (32 KB)
  u16* Wb1  = R1 + 16384;

  const int tid = threadIdx.x, lane = tid & 63, wid = tid >> 6;
  int bid = blockIdx.x;
  bid = (bid & 7) * 32 + (bid >> 3);               // XCD swizzle (256 blocks)
  const int m0  = bid * 64;
  const int l31 = lane & 31, half = lane >> 5;

  // ======================= phase 1: bottom MLP -> dxl =======================
  auto stageW2 = [&](int t, u16* buf) {
    #pragma unroll
    for (int it = 0; it < 4; ++it) {
      int loff = (it * 512 + tid) * 16;
      int row  = loff >> 7, slot = (loff & 127) >> 4, gs = slot ^ (row & 7);
      llds16(buf + (size_t)(it * 512 + (wid << 6)) * 8,
             W2s + (size_t)row * 512 + t * 64 + gs * 8);
    }
  };

  if (tid < 256) {
    int loff = tid * 16, row = loff >> 6, slot = (loff & 63) >> 4, gs = slot ^ (row & 3);
    llds16(Xl + (size_t)(wid << 6) * 8, Xs + (size_t)(m0 + row) * 32 + gs * 8);
  }
  #pragma unroll
  for (int it = 0; it < 4; ++it) {
    int loff = (it * 512 + tid) * 16, row = loff >> 6, slot = (loff & 63) >> 4,
        gs = slot ^ (row & 3);
    llds16(W1l + (size_t)(it * 512 + (wid << 6)) * 8, W1s + (size_t)row * 32 + gs * 8);
  }
  stageW2(0, W2b0);
  asm volatile("s_waitcnt vmcnt(4)" ::: "memory");  // X+W1 landed; W2(0) flying
  __builtin_amdgcn_s_barrier();

  // G1: A1 = relu(X * W1^T + bb1), K=32; wave -> 64 cols
  {
    f32x16 acc1[2][2] = {};
    #pragma unroll
    for (int ks = 0; ks < 2; ++ks) {
      half8 af[2], bf[2];
      #pragma unroll
      for (int mi = 0; mi < 2; ++mi) {
        int row = mi * 32 + l31, sl = (2 * ks + half) ^ (row & 3);
        af[mi] = *(const half8*)(Xl + (size_t)row * 32 + sl * 8);
      }
      #pragma unroll
      for (int ni = 0; ni < 2; ++ni) {
        int row = wid * 64 + ni * 32 + l31, sl = (2 * ks + half) ^ (row & 3);
        bf[ni] = *(const half8*)(W1l + (size_t)row * 32 + sl * 8);
      }
      #pragma unroll
      for (int mi = 0; mi < 2; ++mi)
        #pragma unroll
        for (int ni = 0; ni < 2; ++ni)
          acc1[mi][ni] = __builtin_amdgcn_mfma_f32_32x32x16_f16(af[mi], bf[ni], acc1[mi][ni], 0, 0, 0);
    }
    #pragma unroll
    for (int ni = 0; ni < 2; ++ni) {
      int col = wid * 64 + ni * 32 + l31;
      float bv = bb1[col];
      #pragma unroll
      for (int mi = 0; mi < 2; ++mi)
        #pragma unroll
        for (int reg = 0; reg < 16; ++reg) {
          int row = mi * 32 + crow(reg, half);
          float v = fmaxf(acc1[mi][ni][reg] + bv, 0.f);
          AB[(size_t)row * 512 + (((col >> 3) ^ (row & 63)) * 8) + (col & 7)] = f2h(v);
        }
    }
  }
  __syncthreads();

  // G2: A2 = relu(A1 * W2^T + bb2), K=512, 8 steps BK=64; wave -> 32 cols
  {
    f32x16 acc2[2] = {};
    for (int t = 0; t < 8; ++t) {
      asm volatile("s_waitcnt vmcnt(0)" ::: "memory");
      __builtin_amdgcn_s_barrier();
      if (t < 7) stageW2(t + 1, ((t + 1) & 1) ? W2b1 : W2b0);
      const u16* buf = (t & 1) ? W2b1 : W2b0;
      #pragma unroll
      for (int ks = 0; ks < 4; ++ks) {
        int s = t * 4 + ks;
        half8 af[2], bf;
        #pragma unroll
        for (int mi = 0; mi < 2; ++mi) {
          int row = mi * 32 + l31, sl = (2 * s + half) ^ (row & 63);
          af[mi] = *(const half8*)(AB + (size_t)row * 512 + sl * 8);
        }
        {
          int row = wid * 32 + l31, sl = (2 * ks + half) ^ (row & 7);
          bf = *(const half8*)(buf + (size_t)row * 64 + sl * 8);
        }
        #pragma unroll
        for (int mi = 0; mi < 2; ++mi)
          acc2[mi] = __builtin_amdgcn_mfma_f32_32x32x16_f16(af[mi], bf, acc2[mi], 0, 0, 0);
      }
    }
    // all W2 ds_reads done block-wide; stage W3 (overlays dead W2b1) under epilogue
    asm volatile("s_waitcnt lgkmcnt(0)" ::: "memory");
    __builtin_amdgcn_s_barrier();
    #pragma unroll
    for (int it = 0; it < 4; ++it) {
      int loff = (it * 512 + tid) * 16;
      int row = loff >> 9, slot = (loff & 511) >> 4, gs = slot ^ (row & 31);
      llds16(W3l + (size_t)(it * 512 + (wid << 6)) * 8, W3s + (size_t)row * 256 + gs * 8);
    }
    // epilogue -> A2 (overlays dead W2b0)
    int col = wid * 32 + l31;
    float bv = bb2[col];
    #pragma unroll
    for (int mi = 0; mi < 2; ++mi)
      #pragma unroll
      for (int reg = 0; reg < 16; ++reg) {
        int row = mi * 32 + crow(reg, half);
        float v = fmaxf(acc2[mi][reg] + bv, 0.f);
        A2[(size_t)row * 256 + (((col >> 3) ^ (row & 31)) * 8) + (col & 7)] = f2h(v);
      }
  }
  asm volatile("s_waitcnt vmcnt(0) lgkmcnt(0)" ::: "memory");  // W3 landed; A2 visible
  __builtin_amdgcn_s_barrier();

  // G3: dx = relu(A2 * W3^T + bb3) -> dxl f16 (waves 0-3); SW=7 on 16B slots
  if (wid < 4) {
    f32x16 acc3 = {};
    const int gm = (wid >> 1) * 32, gn = (wid & 1) * 32;
    #pragma unroll
    for (int s = 0; s < 16; ++s) {
      int rowa = gm + l31, sa = (2 * s + half) ^ (rowa & 31);
      half8 a = *(const half8*)(A2 + (size_t)rowa * 256 + sa * 8);
      int rowb = gn + l31, sb = (2 * s + half) ^ (rowb & 31);
      half8 b = *(const half8*)(W3l + (size_t)rowb * 256 + sb * 8);
      acc3 = __builtin_amdgcn_mfma_f32_32x32x16_f16(a, b, acc3, 0, 0, 0);
    }
    #pragma unroll
    for (int reg = 0; reg < 16; ++reg) {
      int col = gn + l31, row = gm + crow(reg, half);
      float v = fmaxf(acc3[reg] + bb3[col], 0.f);
      dxl[(size_t)row * 64 + (((col >> 3) ^ (row & 7)) * 8) + (col & 7)] = f2h(v);
    }
  }
  __syncthreads();

  // ======================= phase 2: gather + Gram -> AB =====================
  // W4 tile [512][32] row-pair-packed; global WT1s is [512][448] (true K)
  auto stageW4 = [&](int t, u16* buf) {
    #pragma unroll
    for (int it = 0; it < 4; ++it) {
      int p  = (it * 512 + tid) * 16;
      int pr = p >> 7, ps = (p & 127) >> 4;
      int un = ps ^ (pr & 7);
      int row = 2 * pr + (un >> 2), ls = un & 3;
      llds16(buf + (size_t)(it * 512 + (wid << 6)) * 8,
             WT1s + (size_t)row * 448 + t * 32 + ls * 8);
    }
  };
  stageW4(0, Wb0);     // overlays dead W3l; flies under the whole gather
  stageW4(1, Wb1);     // overlays dead A2; also flies under the gather

  const int r = l31;
  auto gload = [&](int id, f32x4* buf) {
    if (r >= 1 && r <= 26) {
      const float* src = tables + ((size_t)(r - 1) * VOCAB + (size_t)id) * DIM;
      #pragma unroll
      for (int ks = 0; ks < 4; ++ks) {
        const float* p = src + ks * 16 + half * 8;
        buf[2 * ks]     = *(const f32x4*)(p);
        buf[2 * ks + 1] = *(const f32x4*)(p + 4);
      }
    }
  };
  auto gram = [&](int sr, const f32x4* buf) {
    {
      u16 dv = dxl[(size_t)sr * 64 + (((lane >> 3) ^ (sr & 7)) * 8) + (lane & 7)];
      AB[(size_t)sr * 512 + (((lane >> 3) ^ (sr & 63)) * 8) + (lane & 7)] = dv;
      if (lane < 6) {
        int c = 442 + lane;
        AB[(size_t)sr * 512 + (((c >> 3) ^ (sr & 63)) * 8) + (c & 7)] = 0;
      }
    }
    half8 fh[4];
    #pragma unroll
    for (int ks = 0; ks < 4; ++ks) {
      half8 h = {};
      if (r == 0) {
        int sl = (2 * ks + half) ^ (sr & 7);
        h = *(const half8*)(dxl + (size_t)sr * 64 + sl * 8);
      } else if (r <= 26) {
        f32x4 a = buf[2 * ks], c = buf[2 * ks + 1];
        #pragma unroll
        for (int j = 0; j < 4; ++j) { h[j] = (f16)a[j]; h[j + 4] = (f16)c[j]; }
      }
      fh[ks] = h;
    }
    f32x16 z = {};
    #pragma unroll
    for (int ks = 0; ks < 4; ++ks)
      z = __builtin_amdgcn_mfma_f32_32x32x16_f16(fh[ks], fh[ks], z, 0, 0, 0);
    if (r < 27) {
      #pragma unroll
      for (int reg = 0; reg < 16; ++reg) {
        int rw = crow(reg, half);
        if (rw <= r) {
          int c = 64 + rw * 27 - rw * (rw - 1) / 2 + (r - rw);
          AB[(size_t)sr * 512 + (((c >> 3) ^ (sr & 63)) * 8) + (c & 7)] = f2h(z[reg]);
        }
      }
    }
  };

  {
    f32x4 bufA[8], bufB[8];
    int id0 = (r >= 1 && r <= 26) ? sidx[(size_t)(m0 + wid * 8) * NTAB + (r - 1)] : 0;
    gload(id0, bufA);
    #pragma unroll
    for (int jj = 0; jj < 8; jj += 2) {
      if (jj + 1 < 8) {
        int id = (r >= 1 && r <= 26) ? sidx[(size_t)(m0 + wid * 8 + jj + 1) * NTAB + (r - 1)] : 0;
        gload(id, bufB);
      }
      gram(wid * 8 + jj, bufA);
      if (jj + 2 < 8) {
        int id = (r >= 1 && r <= 26) ? sidx[(size_t)(m0 + wid * 8 + jj + 2) * NTAB + (r - 1)] : 0;
        gload(id, bufA);
      }
      if (jj + 1 < 8) gram(wid * 8 + jj + 1, bufB);
    }
  }
  __syncthreads();

  // ======================= phase 3: top MLP -> out ==========================
  auto stageW5 = [&](int t, u16* buf) {
    #pragma unroll
    for (int it = 0; it < 4; ++it) {
      int loff = (it * 512 + tid) * 16;
      int row = loff >> 7, slot = (loff & 127) >> 4, gs = slot ^ (row & 7);
      llds16(buf + (size_t)(it * 512 + (wid << 6)) * 8,
             WT2s + (size_t)row * 512 + t * 64 + gs * 8);
    }
  };

  // G4: B1 = relu(I * WT1^T + tb1), K=448, 14 steps BK=32; tiles 0+1 prestaged
  {
    f32x16 acc4[2][2] = {};
    for (int t = 0; t < 14; ++t) {
      asm volatile("s_waitcnt vmcnt(0)" ::: "memory");
      __builtin_amdgcn_s_barrier();
      if (t >= 1 && t < 13) stageW4(t + 1, ((t + 1) & 1) ? Wb1 : Wb0);
      const u16* buf = (t & 1) ? Wb1 : Wb0;
      #pragma unroll
      for (int ks = 0; ks < 2; ++ks) {
        int s = t * 2 + ks;
        half8 af[2], bf[2];
        #pragma unroll
        for (int mi = 0; mi < 2; ++mi) {
          int row = mi * 32 + l31, sl = (2 * s + half) ^ (row & 63);
          af[mi] = *(const half8*)(AB + (size_t)row * 512 + sl * 8);
        }
        #pragma unroll
        for (int ni = 0; ni < 2; ++ni) {
          int n = wid * 64 + ni * 32 + l31;
          int pr = n >> 1;
          int ps = (4 * (n & 1) + 2 * ks + half) ^ (pr & 7);
          bf[ni] = *(const half8*)(buf + (size_t)pr * 64 + ps * 8);
        }
        #pragma unroll
        for (int mi = 0; mi < 2; ++mi)
          #pragma unroll
          for (int ni = 0; ni < 2; ++ni)
            acc4[mi][ni] = __builtin_amdgcn_mfma_f32_32x32x16_f16(af[mi], bf[ni], acc4[mi][ni], 0, 0, 0);
      }
    }
    // all I reads + Wb reads done block-wide; stage G5 tiles 0+1 under epilogue
    asm volatile("s_waitcnt lgkmcnt(0)" ::: "memory");
    __builtin_amdgcn_s_barrier();
    stageW5(0, Wb0);                                  // Wb0 last read t=12; dead
    stageW5(1, Wb1);                                  // Wb1 last read t=13; dead
    #pragma unroll
    for (int ni = 0; ni < 2; ++ni) {
      int col = wid * 64 + ni * 32 + l31;
      float bv = tb1[col];
      #pragma unroll
      for (int mi = 0; mi < 2; ++mi)
        #pragma unroll
        for (int reg = 0; reg < 16; ++reg) {
          int row = mi * 32 + crow(reg, half);
          float v = fmaxf(acc4[mi][ni][reg] + bv, 0.f);
          AB[(size_t)row * 512 + (((col >> 3) ^ (row & 63)) * 8) + (col & 7)] = f2h(v);
        }
    }
  }
  asm volatile("s_waitcnt lgkmcnt(0)" ::: "memory");  // B1 visible; stages keep flying
  __builtin_amdgcn_s_barrier();

  // G5: y = relu(B1 * WT2^T + tb2), K=512, 8 steps BK=64; tiles 0+1 prestaged
  {
    f32x16 acc5[2] = {};
    for (int t = 0; t < 8; ++t) {
      asm volatile("s_waitcnt vmcnt(0)" ::: "memory");
      __builtin_amdgcn_s_barrier();
      if (t >= 1 && t < 7) stageW5(t + 1, ((t + 1) & 1) ? Wb1 : Wb0);
      const u16* buf = (t & 1) ? Wb1 : Wb0;
      #pragma unroll
      for (int ks = 0; ks < 4; ++ks) {
        int s = t * 4 + ks;
        half8 af[2], bf;
        #pragma unroll
        for (int mi = 0; mi < 2; ++mi) {
          int row = mi * 32 + l31, sl = (2 * s + half) ^ (row & 63);
          af[mi] = *(const half8*)(AB + (size_t)row * 512 + sl * 8);
        }
        {
          int row = wid * 32 + l31, sl = (2 * ks + half) ^ (row & 7);
          bf = *(const half8*)(buf + (size_t)row * 64 + sl * 8);
        }
        #pragma unroll
        for (int mi = 0; mi < 2; ++mi)
          acc5[mi] = __builtin_amdgcn_mfma_f32_32x32x16_f16(af[mi], bf, acc5[mi], 0, 0, 0);
      }
    }
    int col = wid * 32 + l31;
    float bv = tb2[col], wv = tw3[col];
    #pragma unroll
    for (int mi = 0; mi < 2; ++mi)
      #pragma unroll
      for (int reg = 0; reg < 16; ++reg) {
        float s = fmaxf(acc5[mi][reg] + bv, 0.f) * wv;
        #pragma unroll
        for (int off = 16; off; off >>= 1) s += __shfl_xor(s, off);
        if (l31 == 0) redbuf[wid][mi * 32 + crow(reg, half)] = s;
      }
  }
  __syncthreads();
  if (tid < 64) {
    float s = tb3[0];
    #pragma unroll
    for (int w = 0; w < 8; ++w) s += redbuf[w][tid];
    out[m0 + tid] = 1.f / (1.f + expf(-s));
  }
}

// ----------------------------------------------------------------------------------
extern "C" void kernel_launch(void* const* d_in, const int* in_sizes, int n_in,
                              void* d_out, int out_size, void* d_ws, size_t ws_size,
                              hipStream_t stream)
{
  const float* dense  = (const float*)d_in[0];
  const int*   sidx   = (const int*)d_in[1];
  const float* tables = (const float*)d_in[2];
  const float* bw1 = (const float*)d_in[3];  const float* bb1 = (const float*)d_in[4];
  const float* bw2 = (const float*)d_in[5];  const float* bb2 = (const float*)d_in[6];
  const float* bw3 = (const float*)d_in[7];  const float* bb3 = (const float*)d_in[8];
  const float* tw1 = (const float*)d_in[9];  const float* tb1 = (const float*)d_in[10];
  const float* tw2 = (const float*)d_in[11]; const float* tb2 = (const float*)d_in[12];
  const float* tw3 = (const float*)d_in[13]; const float* tb3 = (const float*)d_in[14];
  float* out = (float*)d_out;

  char* ws = (char*)d_ws;
  size_t off = 0;
  auto alloc = [&](size_t bytes) { size_t o = off; off += (bytes + 1023) & ~(size_t)1023; return o; };

  u16*  Xs   = (u16*)(ws + alloc((size_t)BATCH * 32 * 2));    // [B][32]
  u16*  W1s  = (u16*)(ws + alloc((size_t)512 * 32 * 2));      // [512][32]
  u16*  W2s  = (u16*)(ws + alloc((size_t)256 * 512 * 2));     // [256][512]
  u16*  W3s  = (u16*)(ws + alloc((size_t)64 * 256 * 2));      // [64][256]
  u16*  WT1s = (u16*)(ws + alloc((size_t)512 * 448 * 2));     // [512][448] (true K)
  u16*  WT2s = (u16*)(ws + alloc((size_t)256 * 512 * 2));     // [256][512]
  (void)ws_size; (void)n_in; (void)in_sizes; (void)out_size;

  prep_k<<<640, 256, 0, stream>>>(dense, Xs, bw1, W1s, bw2, W2s, bw3, W3s,
                                  tw1, WT1s, tw2, WT2s);
  mega_k<<<256, 512, 0, stream>>>(Xs, W1s, W2s, W3s, bb1, bb2, bb3, sidx, tables,
                                  WT1s, WT2s, tb1, tb2, tw3, tb3, out);
}